// Round 1
// baseline (1032.123 us; speedup 1.0000x reference)
//
#include <hip/hip_runtime.h>
#include <math.h>

// Problem constants
#define B_   64
#define I_   4096
#define C_   32
#define D_   16
#define ITILES 512   // i-tiles (blocks are 2 per tile: b-halves)
#define IPB    8     // i's per block = I_/ITILES

// ---------------------------------------------------------------------------
// Pass kernel: recomputes u_hat[b,i,c,D] tile-wise from W,x and accumulates
// s_j partial sums into per-itile slabs.
// PASS 0: c_ij uniform (softmax of zeros) -> slab = sum_i u   (1/32 folded later)
// PASS 1: b = u.v1                 -> c=softmax -> slab = sum_i c*u
// PASS 2: b = u.v1 + u.v2          -> c=softmax -> slab = sum_i c*u
// Block: 256 threads = 4 waves. Wave owns 8 b's. Lane: c=lane&31, Dhalf=lane>>5.
// ---------------------------------------------------------------------------
template<int PASS>
__global__ __launch_bounds__(256, 2)
void pass_kernel(const float* __restrict__ Wg, const float* __restrict__ xg,
                 const float* __restrict__ v1g, const float* __restrict__ v2g,
                 float* __restrict__ slab)
{
    // W[i] staged as float4 words, XOR-swizzled within each c-row (64 words)
    // so that ds_read_b128 of (all c, fixed D,dblk) hits the conflict floor.
    __shared__ float4 lds_w[2048];   // 32 KB
    __shared__ float4 lds_x[128];    // 2 KB: 32 b x 4 dblk

    const int tid   = threadIdx.x;
    const int wave  = tid >> 6;
    const int lane  = tid & 63;
    const int c     = lane & 31;
    const int h     = lane >> 5;
    const int D0    = h * 8;
    const int itile = blockIdx.x >> 1;
    const int half  = blockIdx.x & 1;
    const int b0    = half * 32 + wave * 8;   // first of this wave's 8 b's
    const int i0    = itile * IPB;
    const int cswz  = c & 7;

    const float4* W4 = (const float4*)Wg;
    const float4* x4 = (const float4*)xg;

    float s_acc[8][8];   // [j in D-span][bb]
    #pragma unroll
    for (int j = 0; j < 8; ++j)
        #pragma unroll
        for (int bb = 0; bb < 8; ++bb) s_acc[j][bb] = 0.f;

    for (int ii = 0; ii < IPB; ++ii) {
        const int i = i0 + ii;
        __syncthreads();   // previous iteration's LDS reads done
        // ---- stage W[i]: 2048 float4, coalesced global, swizzled LDS write
        #pragma unroll
        for (int k = 0; k < 8; ++k) {
            int idx = tid + 256 * k;
            int w   = idx & 63;
            int cc  = (idx >> 6) & 7;
            lds_w[(idx & ~63) | (w ^ cc)] = W4[(size_t)i * 2048 + idx];
        }
        // ---- stage x[b, i, :] for this half's 32 b's
        if (tid < 128) {
            int b    = half * 32 + (tid >> 2);
            int dblk = tid & 3;
            lds_x[tid] = x4[(size_t)b * 16384 + (size_t)i * 4 + dblk];
        }
        __syncthreads();

        // ---- u_hat compute: u[j][bb] = sum_d W[c,D0+j,d] * x[b0+bb,d]
        float u[8][8];
        #pragma unroll
        for (int j = 0; j < 8; ++j)
            #pragma unroll
            for (int bb = 0; bb < 8; ++bb) u[j][bb] = 0.f;

        #pragma unroll
        for (int dblk = 0; dblk < 4; ++dblk) {
            float4 xv[8];
            #pragma unroll
            for (int bb = 0; bb < 8; ++bb)
                xv[bb] = lds_x[(wave * 8 + bb) * 4 + dblk];   // broadcast
            #pragma unroll
            for (int j = 0; j < 8; ++j) {
                float4 wv = lds_w[c * 64 + ((((D0 + j) << 2) + dblk) ^ cswz)];
                #pragma unroll
                for (int bb = 0; bb < 8; ++bb) {
                    u[j][bb] = fmaf(wv.x, xv[bb].x, u[j][bb]);
                    u[j][bb] = fmaf(wv.y, xv[bb].y, u[j][bb]);
                    u[j][bb] = fmaf(wv.z, xv[bb].z, u[j][bb]);
                    u[j][bb] = fmaf(wv.w, xv[bb].w, u[j][bb]);
                }
            }
        }

        // ---- routing accumulate
        if (PASS == 0) {
            #pragma unroll
            for (int j = 0; j < 8; ++j)
                #pragma unroll
                for (int bb = 0; bb < 8; ++bb) s_acc[j][bb] += u[j][bb];
        } else {
            #pragma unroll
            for (int bb = 0; bb < 8; ++bb) {
                const int b = b0 + bb;
                const float4* vp1 = (const float4*)(v1g + ((size_t)b * 512 + c * 16 + D0));
                float4 va = vp1[0], vb = vp1[1];
                float p = 0.f;
                p = fmaf(u[0][bb], va.x, p); p = fmaf(u[1][bb], va.y, p);
                p = fmaf(u[2][bb], va.z, p); p = fmaf(u[3][bb], va.w, p);
                p = fmaf(u[4][bb], vb.x, p); p = fmaf(u[5][bb], vb.y, p);
                p = fmaf(u[6][bb], vb.z, p); p = fmaf(u[7][bb], vb.w, p);
                if (PASS == 2) {
                    const float4* vp2 = (const float4*)(v2g + ((size_t)b * 512 + c * 16 + D0));
                    float4 wa = vp2[0], wb = vp2[1];
                    p = fmaf(u[0][bb], wa.x, p); p = fmaf(u[1][bb], wa.y, p);
                    p = fmaf(u[2][bb], wa.z, p); p = fmaf(u[3][bb], wa.w, p);
                    p = fmaf(u[4][bb], wb.x, p); p = fmaf(u[5][bb], wb.y, p);
                    p = fmaf(u[6][bb], wb.z, p); p = fmaf(u[7][bb], wb.w, p);
                }
                // combine the two D-halves: lanes l and l^32 share c
                p += __shfl_xor(p, 32);
                // softmax over c (32 values replicated over both halves)
                float m = p;
                m = fmaxf(m, __shfl_xor(m, 16));
                m = fmaxf(m, __shfl_xor(m, 8));
                m = fmaxf(m, __shfl_xor(m, 4));
                m = fmaxf(m, __shfl_xor(m, 2));
                m = fmaxf(m, __shfl_xor(m, 1));
                float e = __expf(p - m);
                float t = e;
                t += __shfl_xor(t, 16);
                t += __shfl_xor(t, 8);
                t += __shfl_xor(t, 4);
                t += __shfl_xor(t, 2);
                t += __shfl_xor(t, 1);
                float cij = __fdividef(e, t);
                #pragma unroll
                for (int j = 0; j < 8; ++j)
                    s_acc[j][bb] = fmaf(cij, u[j][bb], s_acc[j][bb]);
            }
        }
    }

    // ---- write per-itile partial slab (no atomics, no zero-init needed)
    float4* slab4 = (float4*)slab;
    #pragma unroll
    for (int bb = 0; bb < 8; ++bb) {
        int b = b0 + bb;
        size_t base = ((size_t)itile * 32768 + (size_t)b * 512 + (size_t)(c * 16 + D0)) >> 2;
        float4 lo = {s_acc[0][bb], s_acc[1][bb], s_acc[2][bb], s_acc[3][bb]};
        float4 hi = {s_acc[4][bb], s_acc[5][bb], s_acc[6][bb], s_acc[7][bb]};
        slab4[base]     = lo;
        slab4[base + 1] = hi;
    }
}

// ---------------------------------------------------------------------------
// Reduce 512 slabs -> s_j[b,c,D], then squash: v = s/(1+|s|^2)/sqrt(|s|^2+eps)
// 16-thread groups own one (b,c) capsule vector (D=16 contiguous).
// ---------------------------------------------------------------------------
__global__ __launch_bounds__(256)
void reduce_squash(const float* __restrict__ slab, float* __restrict__ out, float scale)
{
    const int o = blockIdx.x * 256 + threadIdx.x;   // o = b*512 + c*16 + D
    float a[8] = {0.f,0.f,0.f,0.f,0.f,0.f,0.f,0.f};
    for (int g = 0; g < 64; ++g) {
        #pragma unroll
        for (int k = 0; k < 8; ++k)
            a[k] += slab[(size_t)(g * 8 + k) * 32768 + o];
    }
    float s = ((a[0] + a[1]) + (a[2] + a[3])) + ((a[4] + a[5]) + (a[6] + a[7]));
    s *= scale;
    float t = s * s;
    t += __shfl_xor(t, 1);
    t += __shfl_xor(t, 2);
    t += __shfl_xor(t, 4);
    t += __shfl_xor(t, 8);
    float r = s / (1.0f + t) / sqrtf(t + 1e-9f);   // faithful to reference squash
    out[o] = r;
}

extern "C" void kernel_launch(void* const* d_in, const int* in_sizes, int n_in,
                              void* d_out, int out_size, void* d_ws, size_t ws_size,
                              hipStream_t stream)
{
    const float* x = (const float*)d_in[0];   // [64, 4096, 16]
    const float* W = (const float*)d_in[1];   // [1, 4096, 32, 16, 16]

    float* slab = (float*)d_ws;                         // 512 * 32768 floats = 64 MB
    float* v1   = slab + (size_t)ITILES * 32768;        // 32768 floats
    float* v2   = v1 + 32768;
    float* out  = (float*)d_out;                        // [64, 32, 16] fp32

    // iter 1: uniform c (=1/32, folded into reduce scale)
    hipLaunchKernelGGL((pass_kernel<0>), dim3(2 * ITILES), dim3(256), 0, stream, W, x, v1, v2, slab);
    hipLaunchKernelGGL(reduce_squash,    dim3(128),        dim3(256), 0, stream, slab, v1, 1.0f / 32.0f);
    // iter 2: b = u.v1
    hipLaunchKernelGGL((pass_kernel<1>), dim3(2 * ITILES), dim3(256), 0, stream, W, x, v1, v2, slab);
    hipLaunchKernelGGL(reduce_squash,    dim3(128),        dim3(256), 0, stream, slab, v2, 1.0f);
    // iter 3: b = u.v1 + u.v2
    hipLaunchKernelGGL((pass_kernel<2>), dim3(2 * ITILES), dim3(256), 0, stream, W, x, v1, v2, slab);
    hipLaunchKernelGGL(reduce_squash,    dim3(128),        dim3(256), 0, stream, slab, out, 1.0f);
}